// Round 9
// baseline (396.971 us; speedup 1.0000x reference)
//
#include <hip/hip_runtime.h>
#include <stdint.h>

#define HW 4096

typedef unsigned short u16;
typedef unsigned int u32;
typedef __attribute__((ext_vector_type(8))) short bf16x8;
typedef __attribute__((ext_vector_type(4))) float f32x4;
typedef __attribute__((address_space(1))) const unsigned int g_u32;
typedef __attribute__((address_space(3))) unsigned int l_u32;

__device__ __forceinline__ u16 f2bf(float f) {
  union { float f; unsigned u; } v; v.f = f;
  unsigned r = v.u + 0x7FFFu + ((v.u >> 16) & 1u);
  return (u16)(r >> 16);
}

__device__ __forceinline__ void gld16(const void* gsrc, void* ldst) {
  __builtin_amdgcn_global_load_lds((g_u32*)(uintptr_t)gsrc, (l_u32*)(uintptr_t)ldst, 16, 0, 0);
}

// ---------- K0: W fp32 -> bf16 (row-major [o][c]) ----------
__global__ void k_wb(const float* __restrict__ W, u16* __restrict__ wb) {
  int g = blockIdx.x * 256 + threadIdx.x;
  float4 v = ((const float4*)W)[g];
  ushort4 o;
  o.x = f2bf(v.x); o.y = f2bf(v.y); o.z = f2bf(v.z); o.w = f2bf(v.w);
  ((ushort4*)wb)[g] = o;
}

// ---------- K1: fused norm + transpose, x read from HBM ONCE via LDS stash ----------
__global__ __launch_bounds__(256) void k_xnt(const float* __restrict__ x,
                                             u16* __restrict__ xnt,
                                             float* __restrict__ nrm) {
  __shared__ float xs[256][65];     // 66.6 KB, pad 65: pass-2 reads conflict-free
  __shared__ float part[4][64];
  __shared__ float invs[64];
  int b = blockIdx.x >> 6;
  int i0 = (blockIdx.x & 63) << 6;
  int il = threadIdx.x & 63;
  int q  = threadIdx.x >> 6;
  const float* xb = x + ((size_t)b << 20);
  float s = 0.f;
  #pragma unroll 8
  for (int k = 0; k < 64; ++k) {
    int c = q * 64 + k;
    float v = xb[((size_t)c << 12) + i0 + il];
    xs[c][il] = v;
    s += v * v;
  }
  part[q][il] = s;
  __syncthreads();
  if (q == 0) {
    float tot = part[0][il] + part[1][il] + part[2][il] + part[3][il];
    float n = fmaxf(sqrtf(tot), 1e-12f);
    nrm[(b << 12) + i0 + il] = n;
    invs[il] = 1.0f / n;
  }
  __syncthreads();
  float iv = invs[il];
  // pass 2 from LDS: wave q -> c-seg [64q,64q+64), lane il -> output row i0+il
  u16* dst = xnt + (((size_t)((b << 12) + i0 + il)) << 8) + q * 64;
  #pragma unroll
  for (int h = 0; h < 8; ++h) {     // 8 c per chunk -> one uint4 store
    u32 wv[4];
    #pragma unroll
    for (int e = 0; e < 4; ++e) {
      float lo = xs[q * 64 + h * 8 + 2 * e][il] * iv;
      float hi = xs[q * 64 + h * 8 + 2 * e + 1][il] * iv;
      wv[e] = (u32)f2bf(lo) | ((u32)f2bf(hi) << 16);
    }
    uint4 p; p.x = wv[0]; p.y = wv[1]; p.z = wv[2]; p.w = wv[3];
    *(uint4*)(dst + h * 8) = p;
  }
}

// ---------- K2: t[b][o][i] = bf16( nrm[i] * sum_c Wb[o][c]*xnt[i][c] + bias[o] ) ----------
__global__ __launch_bounds__(256) void k_tgemm(const u16* __restrict__ wb,
                                               const u16* __restrict__ xnt,
                                               const float* __restrict__ bias,
                                               const float* __restrict__ nrm,
                                               u16* __restrict__ t) {
  int b = blockIdx.x >> 6;
  int i0 = (blockIdx.x & 63) << 6;
  int w = threadIdx.x >> 6, l = threadIdx.x & 63;
  int lr = l & 15, lq = l >> 4;
  const u16* xb = xnt + (((size_t)((b << 12) + i0)) << 8);
  const f32x4 fz = {0.f, 0.f, 0.f, 0.f};
  f32x4 acc[4][4];
  #pragma unroll
  for (int a = 0; a < 4; ++a)
    #pragma unroll
    for (int c = 0; c < 4; ++c) acc[a][c] = fz;
  #pragma unroll 2
  for (int ks = 0; ks < 8; ++ks) {
    bf16x8 af[4], bfm[4];
    #pragma unroll
    for (int mf = 0; mf < 4; ++mf)
      af[mf] = *(const bf16x8*)(wb + ((64 * w + mf * 16 + lr) << 8) + ks * 32 + lq * 8);
    #pragma unroll
    for (int nf = 0; nf < 4; ++nf)
      bfm[nf] = *(const bf16x8*)(xb + ((nf * 16 + lr) << 8) + ks * 32 + lq * 8);
    #pragma unroll
    for (int mf = 0; mf < 4; ++mf)
      #pragma unroll
      for (int nf = 0; nf < 4; ++nf)
        acc[mf][nf] = __builtin_amdgcn_mfma_f32_16x16x32_bf16(af[mf], bfm[nf], acc[mf][nf], 0, 0, 0);
  }
  float nv[4];
  #pragma unroll
  for (int nf = 0; nf < 4; ++nf) nv[nf] = nrm[(b << 12) + i0 + nf * 16 + lr];
  #pragma unroll
  for (int mf = 0; mf < 4; ++mf) {
    int o = 64 * w + mf * 16 + lq * 4;
    #pragma unroll
    for (int r = 0; r < 4; ++r) {
      float bs = bias[o + r];
      u16* dst = t + (((size_t)((b << 8) + o + r)) << 12) + i0;
      #pragma unroll
      for (int nf = 0; nf < 4; ++nf) {
        float tv = acc[mf][nf][r] * nv[nf] + bs;
        dst[nf * 16 + lr] = f2bf(tv);
      }
    }
  }
}

// ---------- K3: fused  out[:, jblk(128)] = sum_i t[:, i(64)] * square(S^T) ----------
// 512 thr / 8 waves, grid 256. CONFLICT-FREE LDS layouts: both Xi and PT are
// stored as permuted 16B-unit arrays so every ds instruction touches a
// CONTIGUOUS 1KB block (addr = base + lane*16) — m134's conflict-free pattern.
//   Xi phys:  unit(row,u) = ks*256 + iwA*128 + if_*64 + (lq*16+lr)
//             (row = iwA*32+if_*16+lr, u = ks*4+lq); realized via per-lane
//             gl_lds SOURCE addresses (LDS dst stays linear, m173).
//   PT phys:  unit(jrow,u) = ((jw2*2+ks)*4+nf)*64 + lq*16 + lr
//             (jrow = jw2*64+nf*16+lr, u = ks*4+lq); pack writes 2 contiguous
//             256B streams per instruction, stage-B reads contiguous 1KB.
__global__ __launch_bounds__(512, 2) void k_main(const u16* __restrict__ xnt,
                                                 const u16* __restrict__ tt,
                                                 float* __restrict__ out) {
  __shared__ __align__(16) char lds[98304];  // Xi0 32K | Xi1 32K | PT0 16K | PT1 16K
  char* XiB[2]; XiB[0] = lds; XiB[1] = lds + 32768;
  char* PTB[2]; PTB[0] = lds + 65536; PTB[1] = lds + 81920;

  int bid = blockIdx.x;
  int b = bid & 7;                           // batch -> XCD round-robin
  int jt = bid >> 3;
  int j0 = jt << 7;                          // JB = 128
  int tid = threadIdx.x;
  int w = tid >> 6, l = tid & 63;
  int lr = l & 15, lq = l >> 4;
  int iwA = w & 1, jwA = w >> 1;             // stage A: [32i x 32j] per wave
  int cw = w >> 1, jw2 = w & 1;              // stage B: [64c x 64j] per wave

  const u16* xb = xnt + ((size_t)b << 20);   // [i][c] row 256 u16
  const u16* tb = tt  + ((size_t)b << 20);   // [c][i] row 4096 u16

  // loop-invariant Xj B-fragments: strip j0 + 32*jwA (32 j), 64 VGPRs
  bf16x8 xj[2][8];
  #pragma unroll
  for (int jf = 0; jf < 2; ++jf) {
    const u16* p = xb + ((size_t)(j0 + 32 * jwA + jf * 16 + lr) << 8) + lq * 8;
    #pragma unroll
    for (int ks = 0; ks < 8; ++ks)
      xj[jf][ks] = *(const bf16x8*)(p + ks * 32);
  }

  const f32x4 fz = {0.f, 0.f, 0.f, 0.f};
  f32x4 acc[4][4];
  #pragma unroll
  for (int a = 0; a < 4; ++a)
    #pragma unroll
    for (int c = 0; c < 4; ++c) acc[a][c] = fz;

  // Xi staging: wave w stages k-group ks=w, op q2 covers rows q2*16..+16.
  // Per-lane source offset (u16 units): row = q2*16+lr, chans w*32+lq*8.
  u32 soff[4];
  #pragma unroll
  for (int q2 = 0; q2 < 4; ++q2)
    soff[q2] = (u32)((q2 * 16 + lr) * 256 + w * 32 + lq * 8);

  auto stageXi = [&](char* dstbase, int tile) {
    int i0s = (tile & 63) << 6;
    const u16* srcb = xb + ((size_t)i0s << 8);
    #pragma unroll
    for (int q2 = 0; q2 < 4; ++q2)
      gld16(srcb + soff[q2], dstbase + (w * 4 + q2) * 1024);
  };

  stageXi(XiB[0], 0);
  asm volatile("s_waitcnt vmcnt(0)" ::: "memory");
  __builtin_amdgcn_s_barrier();

  for (int it = 0; it < 64; ++it) {
    const int cur = it & 1;
    const int i0 = it << 6;
    char* xiC = XiB[cur];
    char* ptC = PTB[cur];

    // pin xj: loop-carried -> compiler cannot rematerialize the loads
    #pragma unroll
    for (int jf = 0; jf < 2; ++jf)
      #pragma unroll
      for (int ks = 0; ks < 8; ++ks)
        asm volatile("" : "+v"(xj[jf][ks]));

    // t-fragments for stage B — issued FIRST so their wait is vmcnt(4)
    bf16x8 tfr[4][2];
    #pragma unroll
    for (int mf = 0; mf < 4; ++mf) {
      const u16* pB = tb + ((size_t)(cw * 64 + mf * 16 + lr) << 12) + i0 + lq * 8;
      tfr[mf][0] = *(const bf16x8*)(pB);
      tfr[mf][1] = *(const bf16x8*)(pB + 32);
    }

    stageXi(XiB[cur ^ 1], it + 1);           // prefetch next Xi tile (4 gl_lds)

    // ---- stage A: D[i][j] = Xi . Xj^T, K=256, from LDS (contiguous 1KB reads) ----
    f32x4 sacc[2][2];
    sacc[0][0] = fz; sacc[0][1] = fz; sacc[1][0] = fz; sacc[1][1] = fz;
    const char* abase = xiC + iwA * 2048 + l * 16;
    __builtin_amdgcn_s_setprio(1);
    #pragma unroll
    for (int if_ = 0; if_ < 2; ++if_) {
      bf16x8 bfr[8];
      #pragma unroll
      for (int ks = 0; ks < 8; ++ks)
        bfr[ks] = *(const bf16x8*)(abase + if_ * 1024 + ks * 4096);
      #pragma unroll
      for (int ks = 0; ks < 8; ++ks) {
        sacc[if_][0] = __builtin_amdgcn_mfma_f32_16x16x32_bf16(bfr[ks], xj[0][ks], sacc[if_][0], 0, 0, 0);
        sacc[if_][1] = __builtin_amdgcn_mfma_f32_16x16x32_bf16(bfr[ks], xj[1][ks], sacc[if_][1], 0, 0, 0);
      }
    }
    __builtin_amdgcn_s_setprio(0);

    // square + pack 4 consecutive i -> one 8B write; per (jf,if_) the 64 lanes
    // stream 512B contiguous (2 x 256B), conflict-free
    #pragma unroll
    for (int jf = 0; jf < 2; ++jf) {
      int jj = jwA * 2 + jf;
      int Ab = (jj >> 2) * 8192 + iwA * 4096 + (jj & 3) * 1024;
      #pragma unroll
      for (int if_ = 0; if_ < 2; ++if_) {
        f32x4 s = sacc[if_][jf];
        u32 w0 = (u32)f2bf(s[0] * s[0]) | ((u32)f2bf(s[1] * s[1]) << 16);
        u32 w1 = (u32)f2bf(s[2] * s[2]) | ((u32)f2bf(s[3] * s[3]) << 16);
        int off = Ab + (if_ * 2 + (lq >> 1)) * 256 + lr * 16 + ((lq & 1) << 3);
        uint2 val; val.x = w0; val.y = w1;
        *(uint2*)(ptC + off) = val;
      }
    }

    asm volatile("s_waitcnt lgkmcnt(0)" ::: "memory");
    __builtin_amdgcn_sched_barrier(0);
    __builtin_amdgcn_s_barrier();            // #1: PT[cur] ready
    __builtin_amdgcn_sched_barrier(0);

    // ---- stage B: acc[64c x 64j] += t_i . P (contiguous 1KB reads) ----
    const char* pbase = ptC + jw2 * 8192 + l * 16;
    __builtin_amdgcn_s_setprio(1);
    #pragma unroll
    for (int ks = 0; ks < 2; ++ks) {
      bf16x8 pfr[4];
      #pragma unroll
      for (int nf = 0; nf < 4; ++nf)
        pfr[nf] = *(const bf16x8*)(pbase + ks * 4096 + nf * 1024);
      #pragma unroll
      for (int mf = 0; mf < 4; ++mf)
        #pragma unroll
        for (int nf = 0; nf < 4; ++nf)
          acc[mf][nf] = __builtin_amdgcn_mfma_f32_16x16x32_bf16(tfr[mf][ks], pfr[nf], acc[mf][nf], 0, 0, 0);
    }
    __builtin_amdgcn_s_setprio(0);

    asm volatile("s_waitcnt vmcnt(0)" ::: "memory");  // gl_lds issued ~a tile ago: free
    __builtin_amdgcn_sched_barrier(0);
    __builtin_amdgcn_s_barrier();            // #2: Xi[next] ready
    __builtin_amdgcn_sched_barrier(0);
  }

  // epilogue: out[b][c][j0+j] fp32
  #pragma unroll
  for (int mf = 0; mf < 4; ++mf) {
    int c = (b << 8) + cw * 64 + mf * 16 + lq * 4;
    #pragma unroll
    for (int nf = 0; nf < 4; ++nf) {
      int j = j0 + jw2 * 64 + nf * 16 + lr;
      float* dst = out + ((size_t)c << 12) + j;
      #pragma unroll
      for (int r = 0; r < 4; ++r)
        dst[(size_t)r << 12] = acc[mf][nf][r];
    }
  }
}

extern "C" void kernel_launch(void* const* d_in, const int* in_sizes, int n_in,
                              void* d_out, int out_size, void* d_ws, size_t ws_size,
                              hipStream_t stream) {
  const float* x    = (const float*)d_in[0];
  const float* W    = (const float*)d_in[1];
  const float* bias = (const float*)d_in[2];
  float* out = (float*)d_out;

  char* ws = (char*)d_ws;
  u16*   xnt = (u16*)(ws);                                  // 16 MiB  [b][i][c] bf16
  u16*   tt  = (u16*)(ws + ((size_t)16 << 20));             // 16 MiB  [b][c][i] bf16
  u16*   wb  = (u16*)(ws + ((size_t)32 << 20));             // 128 KiB
  float* nrm = (float*)(ws + ((size_t)33 << 20));           // 128 KiB

  hipLaunchKernelGGL(k_wb,    dim3(64),  dim3(256), 0, stream, W, wb);
  hipLaunchKernelGGL(k_xnt,   dim3(512), dim3(256), 0, stream, x, xnt, nrm);
  hipLaunchKernelGGL(k_tgemm, dim3(512), dim3(256), 0, stream, wb, xnt, bias, nrm, tt);
  hipLaunchKernelGGL(k_main,  dim3(256), dim3(512), 0, stream, xnt, tt, out);
}